// Round 3
// baseline (310.982 us; speedup 1.0000x reference)
//
#include <hip/hip_runtime.h>

// LSTM fused kernel for MI355X (gfx950) — round 3.
// B=4096, S=256, H=64, input dim 4 (from Linear(1->4)+tanh).
// TB=8 rows/block, grid=512 (2 blocks/CU -> 2 waves/SIMD for latency hiding).
// M=16 MFMA with rows 8..15 pinned to zero; shfl_xor(32) spreads ew over all lanes.
// Recurrent matmul via split-bf16 MFMA (3 independent hi/lo accumulators).

typedef __attribute__((ext_vector_type(8))) __bf16 bf16x8;
typedef __attribute__((ext_vector_type(4))) float f32x4;
typedef __attribute__((ext_vector_type(2))) float f32x2;

#define S_LEN 256
#define HID 64
#define TB 8
#define CHUNK 64
#define LOG2E 1.4426950408889634f

#if defined(__has_builtin) && __has_builtin(__builtin_amdgcn_exp2f)
#define EXP2F(x) __builtin_amdgcn_exp2f(x)
#else
#define EXP2F(x) exp2f(x)
#endif
#if defined(__has_builtin) && __has_builtin(__builtin_amdgcn_rcpf)
#define RCPF(x) __builtin_amdgcn_rcpf(x)
#else
#define RCPF(x) (1.0f / (x))
#endif

__device__ __forceinline__ float fast_sigmoid(float x) {
    float e = EXP2F(-LOG2E * x);
    return RCPF(1.0f + e);
}
__device__ __forceinline__ float fast_tanh(float x) {
    float e = EXP2F(2.0f * LOG2E * x);
    return 1.0f - 2.0f * RCPF(e + 1.0f);
}

__global__ __launch_bounds__(256, 2)
void lstm_fused(const float* __restrict__ x,
                const float* __restrict__ W1, const float* __restrict__ b1,
                const float* __restrict__ W_ih, const float* __restrict__ W_hh,
                const float* __restrict__ b_ih, const float* __restrict__ b_hh,
                const float* __restrict__ W2, const float* __restrict__ b2,
                float* __restrict__ out)
{
    // fc1 chunk: [t_local][row][4]  (8 KB)
    __shared__ float fc1c[CHUNK][TB][4];
    // h double buffer, split hi/lo, k-grouped for MFMA A-frag b128 reads:
    // [buf][hi/lo][kstep][kg][row 0..15 (8..15 stay ZERO)][j]   (8 KB)
    __shared__ __bf16 hbuf[2][2][2][4][16][8];
    // final h for output projection: [unit][row]  (2 KB)
    __shared__ float hfin[HID][TB];

    const int tid  = threadIdx.x;
    const int lane = tid & 63;
    const int wv   = tid >> 6;     // wave 0..3
    const int col  = lane & 15;    // N-col within 16-tile / A-row for loads
    const int kg   = lane >> 4;    // k-group 0..3
    const int b0   = blockIdx.x * TB;

    // ---- W_hh B-fragments (hi/lo), resident in VGPRs for all steps ----
    // wave wv owns N-tiles {wv, wv+4, wv+8, wv+12}: gate n of units [16wv,16wv+16)
    bf16x8 whh_h[4][2], whh_l[4][2];
    float  wihv[4][4];   // W_ih rows (exact fp32 gx path)
    float  biasv[4];     // b_ih + b_hh
    #pragma unroll
    for (int n = 0; n < 4; ++n) {
        const int g = 16 * (wv + 4 * n) + col;
        #pragma unroll
        for (int ks = 0; ks < 2; ++ks) {
            const float* wp = &W_hh[g * 64 + ks * 32 + kg * 8];
            #pragma unroll
            for (int j = 0; j < 8; ++j) {
                float wf  = wp[j];
                __bf16 hi = (__bf16)wf;
                whh_h[n][ks][j] = hi;
                whh_l[n][ks][j] = (__bf16)(wf - (float)hi);
            }
        }
        #pragma unroll
        for (int j = 0; j < 4; ++j) wihv[n][j] = W_ih[g * 4 + j];
        biasv[n] = b_ih[g] + b_hh[g];
    }

    // zero ALL of hbuf (8 KB): h0 = 0 and rows 8..15 must stay 0 forever
    {
        f32x4* z = (f32x4*)&hbuf[0][0][0][0][0][0];
        f32x4 zv = {0.f, 0.f, 0.f, 0.f};
        z[tid] = zv; z[tid + 256] = zv;
    }

    float w1r[4], b1r[4];
    #pragma unroll
    for (int j = 0; j < 4; ++j) { w1r[j] = W1[j]; b1r[j] = b1[j]; }

    // this lane's ew assignment after the shfl_xor(32) redistribution:
    // kg0 -> rows {0,1}, kg1 -> {4,5}, kg2 -> {2,3}, kg3 -> {6,7}
    const int row_base = (kg & 1) * 4 + (kg >> 1) * 2;
    const bool upper   = (kg >= 2);   // uses swapped acc elements 2,3

    f32x2 cst = {0.f, 0.f};           // c for rows row_base, row_base+1 (unit u)
    float hlast[2];

    const int u   = 16 * wv + col;    // this lane's h-unit
    const int uks = u >> 5, ukg = (u >> 3) & 3, up = u & 7;

    for (int t = 0; t < S_LEN; ++t) {
        if ((t & (CHUNK - 1)) == 0) {
            __syncthreads();   // prior chunk reads done (covers zero-init at t=0)
            const int rr = tid & 7;
            const int tq = tid >> 3;     // 0..31, 2 steps each
            f32x2 xv = *(const f32x2*)&x[(b0 + rr) * S_LEN + t + tq * 2];
            #pragma unroll
            for (int tl = 0; tl < 2; ++tl) {
                #pragma unroll
                for (int j = 0; j < 4; ++j)
                    fc1c[tq * 2 + tl][rr][j] = fast_tanh(xv[tl] * w1r[j] + b1r[j]);
            }
            __syncthreads();
        }
        const int cur = t & 1, nxt = cur ^ 1;

        // A fragments: h hi/lo, 2 k-steps (A-row = col, k = kg*8+j)
        bf16x8 ah0 = *(const bf16x8*)&hbuf[cur][0][0][kg][col][0];
        bf16x8 ah1 = *(const bf16x8*)&hbuf[cur][0][1][kg][col][0];
        bf16x8 al0 = *(const bf16x8*)&hbuf[cur][1][0][kg][col][0];
        bf16x8 al1 = *(const bf16x8*)&hbuf[cur][1][1][kg][col][0];

        // 24 MFMAs: 4 N-tiles x 3 independent split-term accumulators (depth-2 chains)
        f32x4 accS[4];
        #pragma unroll
        for (int n = 0; n < 4; ++n) {
            f32x4 z4 = {0.f, 0.f, 0.f, 0.f};
            f32x4 a = __builtin_amdgcn_mfma_f32_16x16x32_bf16(ah0, whh_h[n][0], z4, 0, 0, 0);
            a       = __builtin_amdgcn_mfma_f32_16x16x32_bf16(ah1, whh_h[n][1], a,  0, 0, 0);
            f32x4 b = __builtin_amdgcn_mfma_f32_16x16x32_bf16(al0, whh_h[n][0], z4, 0, 0, 0);
            b       = __builtin_amdgcn_mfma_f32_16x16x32_bf16(al1, whh_h[n][1], b,  0, 0, 0);
            f32x4 c = __builtin_amdgcn_mfma_f32_16x16x32_bf16(ah0, whh_l[n][0], z4, 0, 0, 0);
            c       = __builtin_amdgcn_mfma_f32_16x16x32_bf16(ah1, whh_l[n][1], c,  0, 0, 0);
            accS[n] = (a + b) + c;
        }

        // gx + bias in exact fp32 for this lane's 2 rows (fills MFMA shadow)
        const int tloc = t & (CHUNK - 1);
        float gxv[4][2];
        #pragma unroll
        for (int r = 0; r < 2; ++r) {
            f32x4 fv = *(const f32x4*)&fc1c[tloc][row_base + r][0]; // 16-lane broadcast
            #pragma unroll
            for (int n = 0; n < 4; ++n) {
                float s = biasv[n];
                s = fmaf(fv[0], wihv[n][0], s);
                s = fmaf(fv[1], wihv[n][1], s);
                s = fmaf(fv[2], wihv[n][2], s);
                s = fmaf(fv[3], wihv[n][3], s);
                gxv[n][r] = s;
            }
        }

        // redistribute valid rows: lanes kg>=2 take partner's acc elements 2,3
        // (D row = (lane>>4)*4 + reg; rows 8..15 are zeros and get discarded)
        float gsel[4][2];
        #pragma unroll
        for (int n = 0; n < 4; ++n) {
            float s2 = __shfl_xor(accS[n][2], 32);
            float s3 = __shfl_xor(accS[n][3], 32);
            gsel[n][0] = upper ? s2 : accS[n][0];
            gsel[n][1] = upper ? s3 : accS[n][1];
        }

        // elementwise LSTM update: 2 rows per lane, all 64 lanes active
        #pragma unroll
        for (int r = 0; r < 2; ++r) {
            float iv = fast_sigmoid(gsel[0][r] + gxv[0][r]);
            float fg = fast_sigmoid(gsel[1][r] + gxv[1][r]);
            float gv = fast_tanh   (gsel[2][r] + gxv[2][r]);
            float ov = fast_sigmoid(gsel[3][r] + gxv[3][r]);
            float cv = fg * cst[r] + iv * gv;
            cst[r] = cv;
            float hv = ov * fast_tanh(cv);
            hlast[r] = hv;
            __bf16 hi = (__bf16)hv;
            __bf16 lo = (__bf16)(hv - (float)hi);
            const int rw = row_base + r;
            hbuf[nxt][0][uks][ukg][rw][up] = hi;
            hbuf[nxt][1][uks][ukg][rw][up] = lo;
        }
        __syncthreads();
    }

    // epilogue: out[b] = h_last . W2 + b2
    #pragma unroll
    for (int r = 0; r < 2; ++r) hfin[u][row_base + r] = hlast[r];
    __syncthreads();
    if (tid < TB) {
        float s = b2[0];
        #pragma unroll
        for (int uu = 0; uu < HID; ++uu) s += hfin[uu][tid] * W2[uu];
        out[b0 + tid] = s;
    }
}

extern "C" void kernel_launch(void* const* d_in, const int* in_sizes, int n_in,
                              void* d_out, int out_size, void* d_ws, size_t ws_size,
                              hipStream_t stream) {
    (void)in_sizes; (void)n_in; (void)d_ws; (void)ws_size; (void)out_size;
    const float* x    = (const float*)d_in[0];
    const float* W1   = (const float*)d_in[1];
    const float* b1   = (const float*)d_in[2];
    const float* W_ih = (const float*)d_in[3];
    const float* W_hh = (const float*)d_in[4];
    const float* b_ih = (const float*)d_in[5];
    const float* b_hh = (const float*)d_in[6];
    const float* W2   = (const float*)d_in[7];
    const float* b2   = (const float*)d_in[8];
    float* out = (float*)d_out;
    lstm_fused<<<4096 / TB, 256, 0, stream>>>(x, W1, b1, W_ih, W_hh, b_ih, b_hh, W2, b2, out);
}

// Round 6
// 230.522 us; speedup vs baseline: 1.3490x; 1.3490x over previous
//
#include <hip/hip_runtime.h>

// LSTM fused kernel for MI355X (gfx950) — round 4 design (3rd submit; two prior
// rounds hit GPUAcquisitionTimeout before running).
// B=4096, S=256, H=64, input dim 4 (from Linear(1->4)+tanh).
// grid=256 (1 block/CU), 256 threads (4 waves), TB=16 rows/block. Issue-bound
// regime (R2/R3 counters) -> minimize per-step VALU/trans issue:
//  - gx (fc1 @ W_ih^T) folded into MFMA as a 7th K=32 step (hi/lo exact product)
//  - bias via MFMA C-input (exact fp32, free)
//  - LOG2E pre-scaled into W/bias: sigmoid = rcp(1+exp2(-p)), no arg muls
//  - ping-pong unroll-2 kills buffer-index arithmetic

typedef __attribute__((ext_vector_type(8))) __bf16 bf16x8;
typedef __attribute__((ext_vector_type(4))) float f32x4;

#define S_LEN 256
#define TB 16
#define CHUNK 64
#define LOG2E 1.4426950408889634f

#if defined(__has_builtin) && __has_builtin(__builtin_amdgcn_exp2f)
#define EXP2F(x) __builtin_amdgcn_exp2f(x)
#else
#define EXP2F(x) exp2f(x)
#endif
#if defined(__has_builtin) && __has_builtin(__builtin_amdgcn_rcpf)
#define RCPF(x) __builtin_amdgcn_rcpf(x)
#else
#define RCPF(x) (1.0f / (x))
#endif

__device__ __forceinline__ float fast_tanh(float x) {
    float e = EXP2F(2.0f * LOG2E * x);
    return 1.0f - 2.0f * RCPF(e + 1.0f);
}

#define MFMA16(A, B, C) __builtin_amdgcn_mfma_f32_16x16x32_bf16((A), (B), (C), 0, 0, 0)

// One LSTM step: read h from buffer RB, write h to buffer WB. TLOC = t & 63.
#define STEP(RB, WB, TLOC) do {                                                   \
    bf16x8 ah0 = *(const bf16x8*)&hbuf[RB][0][0][kg][col][0];                     \
    bf16x8 ah1 = *(const bf16x8*)&hbuf[RB][0][1][kg][col][0];                     \
    bf16x8 al0 = *(const bf16x8*)&hbuf[RB][1][0][kg][col][0];                     \
    bf16x8 al1 = *(const bf16x8*)&hbuf[RB][1][1][kg][col][0];                     \
    bf16x8 fa  = *(const bf16x8*)&fcfrag[TLOC][col][0];                           \
    if (kg >= 2) fa = zero8;                                                      \
    f32x4 acc[4];                                                                 \
    _Pragma("unroll")                                                             \
    for (int n = 0; n < 4; ++n) {                                                 \
        f32x4 a = MFMA16(fa,  whx[n],      biasq[n]);  /* gx + bias (exact) */    \
        a       = MFMA16(ah0, whh_h[n][0], a);                                    \
        a       = MFMA16(ah1, whh_h[n][1], a);                                    \
        a       = MFMA16(al0, whh_h[n][0], a);                                    \
        a       = MFMA16(al1, whh_h[n][1], a);                                    \
        a       = MFMA16(ah0, whh_l[n][0], a);                                    \
        a       = MFMA16(ah1, whh_l[n][1], a);                                    \
        acc[n] = a;                                                               \
    }                                                                             \
    _Pragma("unroll")                                                             \
    for (int r = 0; r < 4; ++r) {                                                 \
        /* preacts are pre-scaled by LOG2E (2*LOG2E for g-gate) */                \
        float ei = EXP2F(-acc[0][r]); float iv = RCPF(1.0f + ei);                 \
        float ef = EXP2F(-acc[1][r]); float fv = RCPF(1.0f + ef);                 \
        float eg = EXP2F( acc[2][r]); float gv = 1.0f - 2.0f * RCPF(1.0f + eg);   \
        float eo = EXP2F(-acc[3][r]); float ov = RCPF(1.0f + eo);                 \
        float cv = fv * cst[r] + iv * gv; cst[r] = cv;                            \
        float ec = EXP2F((2.0f * LOG2E) * cv);                                    \
        float th = 1.0f - 2.0f * RCPF(1.0f + ec);                                 \
        float hv = ov * th; hlast[r] = hv;                                        \
        __bf16 hi = (__bf16)hv; __bf16 lo = (__bf16)(hv - (float)hi);             \
        hbuf[WB][0][uks][ukg][kg * 4 + r][up] = hi;                               \
        hbuf[WB][1][uks][ukg][kg * 4 + r][up] = lo;                               \
    }                                                                             \
    __syncthreads();                                                              \
} while (0)

__global__ __launch_bounds__(256, 1)
void lstm_fused(const float* __restrict__ x,
                const float* __restrict__ W1, const float* __restrict__ b1,
                const float* __restrict__ W_ih, const float* __restrict__ W_hh,
                const float* __restrict__ b_ih, const float* __restrict__ b_hh,
                const float* __restrict__ W2, const float* __restrict__ b2,
                float* __restrict__ out)
{
    // fc1 A-fragments, frag-ready: [t][row][ f_hi(4) | f_lo(4) ]  (16 KB)
    __shared__ __bf16 fcfrag[CHUNK][TB][8];
    // h double buffer, split hi/lo, k-grouped: [buf][hl][ks][kg][row][j] (16 KB)
    __shared__ __bf16 hbuf[2][2][2][4][TB][8];
    // final h for output projection  (4 KB)
    __shared__ float hfin[64][TB];

    const int tid  = threadIdx.x;
    const int lane = tid & 63;
    const int wv   = tid >> 6;     // wave 0..3
    const int col  = lane & 15;    // A-row / D-col
    const int kg   = lane >> 4;    // k-group 0..3
    const int b0   = blockIdx.x * TB;

    // ---- weights (LOG2E-pre-scaled), resident in VGPRs ----
    bf16x8 whh_h[4][2], whh_l[4][2];  // W_hh hi/lo per tile/kstep
    bf16x8 whx[4];                    // gx B-frag: kg0=[Whi|Whi], kg1=[Wlo|Wlo], else 0
    f32x4  biasq[4];                  // scaled bias splat (MFMA C-input)

    bf16x8 zero8;
    #pragma unroll
    for (int j = 0; j < 8; ++j) zero8[j] = (__bf16)0.0f;

    #pragma unroll
    for (int n = 0; n < 4; ++n) {
        const int g = 16 * (wv + 4 * n) + col;          // n: 0=i,1=f,2=g,3=o
        const float sc = (n == 2) ? (2.0f * LOG2E) : LOG2E;
        #pragma unroll
        for (int ks = 0; ks < 2; ++ks) {
            const float* wp = &W_hh[g * 64 + ks * 32 + kg * 8];
            #pragma unroll
            for (int j = 0; j < 8; ++j) {
                float wf  = sc * wp[j];
                __bf16 hi = (__bf16)wf;
                whh_h[n][ks][j] = hi;
                whh_l[n][ks][j] = (__bf16)(wf - (float)hi);
            }
        }
        whx[n] = zero8;
        if (kg < 2) {
            #pragma unroll
            for (int j = 0; j < 4; ++j) {
                float wf  = sc * W_ih[g * 4 + j];
                __bf16 hi = (__bf16)wf;
                __bf16 v  = (kg == 0) ? hi : (__bf16)(wf - (float)hi);
                whx[n][j] = v; whx[n][j + 4] = v;
            }
        }
        const float bs = sc * (b_ih[g] + b_hh[g]);
        biasq[n][0] = bs; biasq[n][1] = bs; biasq[n][2] = bs; biasq[n][3] = bs;
    }

    // zero h0 (buffer 0 = first 4 KB of hbuf)
    {
        f32x4 zv = {0.f, 0.f, 0.f, 0.f};
        ((f32x4*)&hbuf[0][0][0][0][0][0])[tid] = zv;
    }

    float w1r[4], b1r[4];
    #pragma unroll
    for (int j = 0; j < 4; ++j) { w1r[j] = W1[j]; b1r[j] = b1[j]; }

    float cst[4] = {0.f, 0.f, 0.f, 0.f};
    float hlast[4];

    const int u   = 16 * wv + col;    // this lane's h-unit
    const int uks = u >> 5, ukg = (u >> 3) & 3, up = u & 7;

    for (int t = 0; t < S_LEN; t += 2) {
        if ((t & (CHUNK - 1)) == 0) {
            __syncthreads();   // prior chunk's fcfrag reads done (covers init at t=0)
            const int rr = tid & 15;
            const int tq = tid >> 4;         // 0..15, 4 steps each
            f32x4 xv = *(const f32x4*)&x[(b0 + rr) * S_LEN + t + tq * 4];
            #pragma unroll
            for (int tl = 0; tl < 4; ++tl) {
                bf16x8 v;
                #pragma unroll
                for (int j = 0; j < 4; ++j) {
                    float fc  = fast_tanh(xv[tl] * w1r[j] + b1r[j]);
                    __bf16 hi = (__bf16)fc;
                    v[j]     = hi;
                    v[j + 4] = (__bf16)(fc - (float)hi);
                }
                *(bf16x8*)&fcfrag[tq * 4 + tl][rr][0] = v;
            }
            __syncthreads();
        }
        STEP(0, 1, (t & (CHUNK - 1)));
        STEP(1, 0, ((t + 1) & (CHUNK - 1)));
    }

    // epilogue: out[b] = h_last . W2 + b2
    #pragma unroll
    for (int r = 0; r < 4; ++r) hfin[u][kg * 4 + r] = hlast[r];
    __syncthreads();
    if (tid < TB) {
        float s = b2[0];
        #pragma unroll
        for (int uu = 0; uu < 64; ++uu) s += hfin[uu][tid] * W2[uu];
        out[b0 + tid] = s;
    }
}

extern "C" void kernel_launch(void* const* d_in, const int* in_sizes, int n_in,
                              void* d_out, int out_size, void* d_ws, size_t ws_size,
                              hipStream_t stream) {
    (void)in_sizes; (void)n_in; (void)d_ws; (void)ws_size; (void)out_size;
    const float* x    = (const float*)d_in[0];
    const float* W1   = (const float*)d_in[1];
    const float* b1   = (const float*)d_in[2];
    const float* W_ih = (const float*)d_in[3];
    const float* W_hh = (const float*)d_in[4];
    const float* b_ih = (const float*)d_in[5];
    const float* b_hh = (const float*)d_in[6];
    const float* W2   = (const float*)d_in[7];
    const float* b2   = (const float*)d_in[8];
    float* out = (float*)d_out;
    lstm_fused<<<4096 / TB, 256, 0, stream>>>(x, W1, b1, W_ih, W_hh, b_ih, b_hh, W2, b2, out);
}